// Round 1
// baseline (352.203 us; speedup 1.0000x reference)
//
#include <hip/hip_runtime.h>

// VQ-VAE vector quantizer, MI355X fp32 baseline.
// latents: [B=64, D=64, H=64, W=64] f32, embedding: [K=512, D=64] f32.
// out: [B,D,H,W] quantized (16777216 f32) + vq_loss scalar (1 f32).
//
// score(n,k) = 0.5*||e_k||^2 - lat_n . e_k  (same argmin as full sq-distance)
// loss      = 1.25/ (N*D) * sum_n ( ||lat_n||^2 + 2*score_best(n) )

#define KCODES 512
#define DDIM   64
#define HW     4096   // H*W
#define NPOS   262144 // B*H*W

// ws layout (floats): [0] = loss accumulator; [16 .. 16+K) = 0.5*||e_k||^2
__global__ __launch_bounds__(512) void vq_prep(const float* __restrict__ emb,
                                               float* __restrict__ wsf) {
    int k = threadIdx.x;
    if (k == 0) wsf[0] = 0.0f;
    float s = 0.0f;
#pragma unroll
    for (int d = 0; d < DDIM; ++d) {
        float e = emb[k * DDIM + d];
        s = fmaf(e, e, s);
    }
    wsf[16 + k] = 0.5f * s;
}

__global__ __launch_bounds__(256) void vq_main(const float* __restrict__ lat,
                                               const float* __restrict__ emb,
                                               float* __restrict__ out,
                                               float* __restrict__ wsf) {
    const int n = blockIdx.x * 256 + threadIdx.x;
    const int b = n >> 12;            // n / (H*W)
    const int hw = n & 4095;          // h*64 + w  (lane == w within a wave)
    const int base = b * (DDIM * HW) + hw;   // + d*HW indexes [b,d,h,w]

    // Load this position's latent vector (coalesced across lanes per d).
    float l[DDIM];
    float l2 = 0.0f;
#pragma unroll
    for (int d = 0; d < DDIM; ++d) {
        float v = lat[base + d * HW];
        l[d] = v;
        l2 = fmaf(v, v, l2);
    }

    const float* __restrict__ cc = wsf + 16;

    float bestv = 3.4e38f;
    int bestk = 0;
    // Hot loop: 512 codes x 64 dims of fp32 FMA. emb/cc addresses are
    // wave-uniform -> scalar loads, SGPR operand in v_fma_f32.
    for (int k = 0; k < KCODES; k += 2) {
        const float* __restrict__ e0 = emb + k * DDIM;
        const float* __restrict__ e1 = e0 + DDIM;
        float s0a = cc[k],     s0b = 0.0f;
        float s1a = cc[k + 1], s1b = 0.0f;
#pragma unroll
        for (int d = 0; d < DDIM; d += 2) {
            s0a = fmaf(-l[d],     e0[d],     s0a);
            s0b = fmaf(-l[d + 1], e0[d + 1], s0b);
            s1a = fmaf(-l[d],     e1[d],     s1a);
            s1b = fmaf(-l[d + 1], e1[d + 1], s1b);
        }
        float s0 = s0a + s0b;
        float s1 = s1a + s1b;
        if (s0 < bestv) { bestv = s0; bestk = k; }
        if (s1 < bestv) { bestv = s1; bestk = k + 1; }
    }

    // Gather the winning code row (scattered dwordx4, L2-resident 128 KB)
    // and write the transposed output: for fixed d, lanes (=w) are coalesced.
    const float4* __restrict__ q4 =
        reinterpret_cast<const float4*>(emb + bestk * DDIM);
#pragma unroll
    for (int j = 0; j < DDIM / 4; ++j) {
        float4 v = q4[j];
        out[base + (4 * j + 0) * HW] = v.x;
        out[base + (4 * j + 1) * HW] = v.y;
        out[base + (4 * j + 2) * HW] = v.z;
        out[base + (4 * j + 3) * HW] = v.w;
    }

    // Loss partial: ||l||^2 + 2*score_best  ==  sum_d (q-l)^2  (exact identity)
    float p = fmaf(2.0f, bestv, l2);
#pragma unroll
    for (int off = 32; off > 0; off >>= 1) p += __shfl_down(p, off, 64);
    if ((threadIdx.x & 63) == 0) atomicAdd(wsf, p);
}

__global__ void vq_finish(const float* __restrict__ wsf,
                          float* __restrict__ out, int out_size) {
    out[out_size - 1] = wsf[0] * (1.25f / 16777216.0f);
}

extern "C" void kernel_launch(void* const* d_in, const int* in_sizes, int n_in,
                              void* d_out, int out_size, void* d_ws, size_t ws_size,
                              hipStream_t stream) {
    const float* lat = (const float*)d_in[0];   // [64,64,64,64]
    const float* emb = (const float*)d_in[1];   // [512,64]
    float* out = (float*)d_out;
    float* wsf = (float*)d_ws;                  // needs (16+512)*4 = 2112 B

    vq_prep<<<1, KCODES, 0, stream>>>(emb, wsf);
    vq_main<<<NPOS / 256, 256, 0, stream>>>(lat, emb, out, wsf);
    vq_finish<<<1, 1, 0, stream>>>(wsf, out, out_size);
}

// Round 2
// 193.938 us; speedup vs baseline: 1.8161x; 1.8161x over previous
//
#include <hip/hip_runtime.h>
#include <hip/hip_bf16.h>

// VQ-VAE quantizer via bf16 MFMA. lat [64,64,64,64] f32, emb [512,64] f32.
// score(n,k) = 0.5||e_k||^2 - l_n.e_k  (argmin-equivalent to sq-distance)
// loss = 1.25/(N*D) * sum_n (||l_n||^2 + 2*score_best(n))
// A-operand = -lat (bf16), C-init = cc  =>  mfma acc ends as score directly.

#define KCODES 512
#define DDIM   64
#define HW     4096
#define BHW    262144   // DDIM*HW, elems per batch slab

typedef __bf16 bf16x8 __attribute__((ext_vector_type(8)));
typedef float  f32x4  __attribute__((ext_vector_type(4)));

__global__ __launch_bounds__(512, 4) void vq_mfma(
    const float* __restrict__ lat,
    const float* __restrict__ emb,
    float* __restrict__ out,
    float* __restrict__ wsf)
{
  // 64 KB swizzled bf16 embedding + 2 KB cc table
  __shared__ char  Bs[KCODES * DDIM * 2];
  __shared__ float ccs[KCODES];

  const int tid = threadIdx.x;

  // ---- stage embedding (bf16, XOR-swizzled 16B granules) + cc = 0.5||e||^2
  // granule G = code*8 + gr (16 B = 8 bf16). Coalesced: consecutive tid ->
  // consecutive 32 B of emb. Swizzle: byte ^= (code&7)<<4 (bits 4-6), same
  // involution applied on the read side below (rule: both-sides-or-neither).
#pragma unroll
  for (int r = 0; r < 8; ++r) {
    int G = tid + 512 * r;            // 0..4095
    int code = G >> 3, gr = G & 7;
    const float4* s = (const float4*)(emb + G * 8);
    float4 x = s[0], y = s[1];
    bf16x8 h;
    h[0] = (__bf16)x.x; h[1] = (__bf16)x.y; h[2] = (__bf16)x.z; h[3] = (__bf16)x.w;
    h[4] = (__bf16)y.x; h[5] = (__bf16)y.y; h[6] = (__bf16)y.z; h[7] = (__bf16)y.w;
    int wa = (code * 128 + gr * 16) ^ ((code & 7) << 4);
    *(bf16x8*)(Bs + wa) = h;
    float p = x.x*x.x + x.y*x.y + x.z*x.z + x.w*x.w
            + y.x*y.x + y.y*y.y + y.z*y.z + y.w*y.w;
    p += __shfl_xor(p, 1); p += __shfl_xor(p, 2); p += __shfl_xor(p, 4);
    if ((tid & 7) == 0) ccs[code] = 0.5f * p;   // gr==0 lane owns this code
  }
  __syncthreads();

  const int lane = tid & 63;
  const int wid  = tid >> 6;
  const int L15  = lane & 15;          // A-row / C-col / position offset
  const int g    = lane >> 4;          // k-group

  // one 64-position group per wave: 4 tiles of 16 positions
  const int gw    = blockIdx.x * 8 + wid;     // 0..4095
  const int nb0   = gw * 64;
  const int bslab = nb0 >> 12;
  const int hw0   = nb0 & 4095;               // 64-aligned, tiles stay in-slab
  const float* __restrict__ lbase = lat + bslab * BHW + hw0 + L15;

  // ---- A fragments (negated bf16) + fp32 ||l||^2 partials
  float  l2_acc = 0.f;
  bf16x8 af[4][2];
#pragma unroll
  for (int t = 0; t < 4; ++t) {
    const float* lt = lbase + t * 16;
#pragma unroll
    for (int kk = 0; kk < 2; ++kk) {
#pragma unroll
      for (int i = 0; i < 8; ++i) {
        float v = lt[(kk * 32 + g * 8 + i) * HW];
        l2_acc = fmaf(v, v, l2_acc);
        af[t][kk][i] = (__bf16)(-v);
      }
    }
  }

  // ---- main loop: 32 chunks of 16 codes
  float bv[4][4];
  int   bk[4][4];
#pragma unroll
  for (int t = 0; t < 4; ++t)
#pragma unroll
    for (int j = 0; j < 4; ++j) { bv[t][j] = 3.4e38f; bk[t][j] = 0; }

  for (int c = 0; c < 32; ++c) {
    const int   code = c * 16 + L15;
    const float cc   = ccs[code];
    const int   ba   = (code * 128 + g * 16) ^ ((code & 7) << 4);
    bf16x8 b0 = *(const bf16x8*)(Bs + ba);
    bf16x8 b1 = *(const bf16x8*)(Bs + (ba ^ 64));   // kk=1: +64 commutes w/ XOR
#pragma unroll
    for (int t = 0; t < 4; ++t) {
      f32x4 acc = {cc, cc, cc, cc};
      acc = __builtin_amdgcn_mfma_f32_16x16x32_bf16(af[t][0], b0, acc, 0, 0, 0);
      acc = __builtin_amdgcn_mfma_f32_16x16x32_bf16(af[t][1], b1, acc, 0, 0, 0);
#pragma unroll
      for (int j = 0; j < 4; ++j) {
        if (acc[j] < bv[t][j]) { bv[t][j] = acc[j]; bk[t][j] = code; }
      }
    }
  }

  // ---- epilogue per tile: argmin-reduce across 16 cols, gather, write
  float bvsum = 0.f;
#pragma unroll
  for (int t = 0; t < 4; ++t) {
    float vr[4]; int kr[4];
#pragma unroll
    for (int j = 0; j < 4; ++j) {
      float v = bv[t][j]; int k = bk[t][j];
#pragma unroll
      for (int m = 1; m < 16; m <<= 1) {
        float ov = __shfl_xor(v, m);
        int   ok = __shfl_xor(k, m);
        if (ov < v || (ov == v && ok < k)) { v = ov; k = ok; }
      }
      vr[j] = v; kr[j] = k;   // row 4g+j best, uniform in 16-lane group
    }
    if (L15 == 0) bvsum += vr[0] + vr[1] + vr[2] + vr[3];

    // lane wants row L15: source group g' = L15>>2 (lane g'*16), reg j = L15&3
    const int src = (L15 >> 2) << 4;
    int r0 = __shfl(kr[0], src), r1 = __shfl(kr[1], src);
    int r2 = __shfl(kr[2], src), r3 = __shfl(kr[3], src);
    const int sel = L15 & 3;
    int k01 = (sel & 1) ? r1 : r0;
    int k23 = (sel & 1) ? r3 : r2;
    const int myk = (sel & 2) ? k23 : k01;

    // gather fp32 row (L2-hot) and write transposed output
    const int dbase = g * 16;
    const float4* q = (const float4*)(emb + myk * 64 + dbase);
    float* ob = out + bslab * BHW + dbase * HW + hw0 + t * 16 + L15;
#pragma unroll
    for (int p4 = 0; p4 < 4; ++p4) {
      float4 vq = q[p4];
      ob[(4 * p4 + 0) * HW] = vq.x;
      ob[(4 * p4 + 1) * HW] = vq.y;
      ob[(4 * p4 + 2) * HW] = vq.z;
      ob[(4 * p4 + 3) * HW] = vq.w;
    }
  }

  // ---- loss partial: sum(||l||^2) + 2*sum(bestv)
  float p = fmaf(2.f, bvsum, l2_acc);
#pragma unroll
  for (int off = 32; off; off >>= 1) p += __shfl_down(p, off);
  if (lane == 0) atomicAdd(wsf, p);
}

__global__ void vq_finish(const float* __restrict__ wsf,
                          float* __restrict__ out, int out_size) {
  out[out_size - 1] = wsf[0] * (1.25f / 16777216.0f);
}

extern "C" void kernel_launch(void* const* d_in, const int* in_sizes, int n_in,
                              void* d_out, int out_size, void* d_ws, size_t ws_size,
                              hipStream_t stream) {
  const float* lat = (const float*)d_in[0];
  const float* emb = (const float*)d_in[1];
  float* out = (float*)d_out;
  float* wsf = (float*)d_ws;

  hipMemsetAsync(d_ws, 0, 4, stream);
  vq_mfma<<<512, 512, 0, stream>>>(lat, emb, out, wsf);
  vq_finish<<<1, 1, 0, stream>>>(wsf, out, out_size);
}

// Round 3
// 171.437 us; speedup vs baseline: 2.0544x; 1.1312x over previous
//
#include <hip/hip_runtime.h>
#include <hip/hip_bf16.h>

// VQ-VAE quantizer via bf16 MFMA. lat [64,64,64,64] f32, emb [512,64] f32.
// score(n,k) = 0.5||e_k||^2 - l_n.e_k  (argmin-equivalent to sq-distance)
// loss = 1.25/(N*D) * sum_n (||l_n||^2 + 2*score_best(n))
// A-operand = -lat (bf16), C-init = cc  =>  mfma acc ends as score directly.

#define KCODES 512
#define DDIM   64
#define HW     4096
#define BHW    262144   // DDIM*HW, elems per batch slab

typedef __bf16 bf16x8 __attribute__((ext_vector_type(8)));
typedef float  f32x4  __attribute__((ext_vector_type(4)));

// launch_bounds (512, 2): LDS (66 KB) already limits to 2 blocks/CU, so a
// 2-waves/EU floor costs nothing and doubles the VGPR budget to 256.
// Round-2's (512,4) produced a 64-VGPR allocation that spilled the A
// fragments to scratch (WRITE_SIZE 103 MB vs 67 ideal) -> latency-bound.
__global__ __launch_bounds__(512, 2) void vq_mfma(
    const float* __restrict__ lat,
    const float* __restrict__ emb,
    float* __restrict__ out,
    float* __restrict__ wsf)
{
  __shared__ char  Bs[KCODES * DDIM * 2];   // 64 KB bf16 emb, XOR-swizzled
  __shared__ float ccs[KCODES];             // 0.5*||e_k||^2

  const int tid = threadIdx.x;

  // ---- stage embedding (bf16, 16B granules, byte ^= (code&7)<<4) + cc
#pragma unroll
  for (int r = 0; r < 8; ++r) {
    int G = tid + 512 * r;            // 0..4095 = code*8 + gr
    int code = G >> 3, gr = G & 7;
    const float4* s = (const float4*)(emb + G * 8);
    float4 x = s[0], y = s[1];
    bf16x8 h;
    h[0] = (__bf16)x.x; h[1] = (__bf16)x.y; h[2] = (__bf16)x.z; h[3] = (__bf16)x.w;
    h[4] = (__bf16)y.x; h[5] = (__bf16)y.y; h[6] = (__bf16)y.z; h[7] = (__bf16)y.w;
    int wa = (code * 128 + gr * 16) ^ ((code & 7) << 4);
    *(bf16x8*)(Bs + wa) = h;
    float p = x.x*x.x + x.y*x.y + x.z*x.z + x.w*x.w
            + y.x*y.x + y.y*y.y + y.z*y.z + y.w*y.w;
    p += __shfl_xor(p, 1); p += __shfl_xor(p, 2); p += __shfl_xor(p, 4);
    if ((tid & 7) == 0) ccs[code] = 0.5f * p;
  }
  __syncthreads();

  const int lane = tid & 63;
  const int wid  = tid >> 6;
  const int L15  = lane & 15;          // A-row(pos) / B-col(code)
  const int g    = lane >> 4;          // k-octet selector

  // one 64-position group per wave: 4 MFMA tiles of 16 positions
  const int gw    = blockIdx.x * 8 + wid;     // 0..4095
  const int nb0   = gw * 64;
  const int bslab = nb0 >> 12;
  const int hw0   = nb0 & 4095;               // 64-aligned
  const float* __restrict__ lbase = lat + bslab * BHW + hw0 + L15;

  // ---- A fragments (negated bf16) + fp32 ||l||^2 partial
  float  l2_acc = 0.f;
  bf16x8 af[4][2];
#pragma unroll
  for (int t = 0; t < 4; ++t) {
    const float* lt = lbase + t * 16;
#pragma unroll
    for (int kk = 0; kk < 2; ++kk) {
#pragma unroll
      for (int i = 0; i < 8; ++i) {
        float v = lt[(kk * 32 + g * 8 + i) * HW];
        l2_acc = fmaf(v, v, l2_acc);
        af[t][kk][i] = (__bf16)(-v);
      }
    }
  }

  // ---- main loop: 32 chunks of 16 codes. D[row=pos(4g+j), col=code(L15)].
  float bv[4][4];
  int   bk[4][4];
#pragma unroll
  for (int t = 0; t < 4; ++t)
#pragma unroll
    for (int j = 0; j < 4; ++j) { bv[t][j] = 3.4e38f; bk[t][j] = 0; }

  for (int c = 0; c < 32; ++c) {
    const int   code = c * 16 + L15;
    const float cc   = ccs[code];
    const int   ba   = (code * 128 + g * 16) ^ ((code & 7) << 4);
    bf16x8 b0 = *(const bf16x8*)(Bs + ba);
    bf16x8 b1 = *(const bf16x8*)(Bs + (ba ^ 64));   // +64 commutes (bit6 clear)
#pragma unroll
    for (int t = 0; t < 4; ++t) {
      f32x4 acc = {cc, cc, cc, cc};
      acc = __builtin_amdgcn_mfma_f32_16x16x32_bf16(af[t][0], b0, acc, 0, 0, 0);
      acc = __builtin_amdgcn_mfma_f32_16x16x32_bf16(af[t][1], b1, acc, 0, 0, 0);
#pragma unroll
      for (int j = 0; j < 4; ++j) {
        if (acc[j] < bv[t][j]) { bv[t][j] = acc[j]; bk[t][j] = code; }
      }
    }
  }

  // ---- epilogue: per tile, monotone-key argmin reduce over 16 cols
  float ssum = 0.f;   // sum over tiles of this lane's row-best score (x4 dup)
#pragma unroll
  for (int t = 0; t < 4; ++t) {
    unsigned kk4[4];
#pragma unroll
    for (int j = 0; j < 4; ++j) {
      unsigned b = __float_as_uint(bv[t][j]);
      unsigned u = b ^ ((unsigned)((int)b >> 31) | 0x80000000u);
      kk4[j] = (u & 0xFFFFFE00u) | (unsigned)bk[t][j];
#pragma unroll
      for (int m = 1; m < 16; m <<= 1)
        kk4[j] = min(kk4[j], (unsigned)__shfl_xor((int)kk4[j], m));
    }
    // lane serves row L15: source group L15>>2 (its lane 16*(L15>>2)), reg L15&3
    const int src = (L15 >> 2) << 4;
    unsigned r0 = (unsigned)__shfl((int)kk4[0], src);
    unsigned r1 = (unsigned)__shfl((int)kk4[1], src);
    unsigned r2 = (unsigned)__shfl((int)kk4[2], src);
    unsigned r3 = (unsigned)__shfl((int)kk4[3], src);
    unsigned k01 = (L15 & 1) ? r1 : r0;
    unsigned k23 = (L15 & 1) ? r3 : r2;
    unsigned kf  = (L15 & 2) ? k23 : k01;
    const int myk = (int)(kf & 0x1FFu);

    // recover best score for the loss (low 9 bits truncated, err <= 2^-9 rel)
    unsigned ub = kf & 0xFFFFFE00u;
    unsigned bb = (ub & 0x80000000u) ? (ub ^ 0x80000000u) : ~ub;
    ssum += __uint_as_float(bb);

    // gather fp32 winning row (L2-hot) and write transposed output
    const int dbase = g * 16;
    const float4* q = (const float4*)(emb + myk * 64 + dbase);
    float* ob = out + bslab * BHW + dbase * HW + hw0 + t * 16 + L15;
#pragma unroll
    for (int p4 = 0; p4 < 4; ++p4) {
      float4 vq = q[p4];
      ob[(4 * p4 + 0) * HW] = vq.x;
      ob[(4 * p4 + 1) * HW] = vq.y;
      ob[(4 * p4 + 2) * HW] = vq.z;
      ob[(4 * p4 + 3) * HW] = vq.w;
    }
  }

  // ---- loss partial: Sum l2 + 2*Sum bestv ; ssum counts each pos 4x
  float p = fmaf(0.5f, ssum, l2_acc);
#pragma unroll
  for (int off = 32; off; off >>= 1) p += __shfl_down(p, off);
  if (lane == 0) atomicAdd(wsf, p);
}

__global__ void vq_finish(const float* __restrict__ wsf,
                          float* __restrict__ out, int out_size) {
  out[out_size - 1] = wsf[0] * (1.25f / 16777216.0f);
}

extern "C" void kernel_launch(void* const* d_in, const int* in_sizes, int n_in,
                              void* d_out, int out_size, void* d_ws, size_t ws_size,
                              hipStream_t stream) {
  const float* lat = (const float*)d_in[0];
  const float* emb = (const float*)d_in[1];
  float* out = (float*)d_out;
  float* wsf = (float*)d_ws;

  hipMemsetAsync(d_ws, 0, 4, stream);
  vq_mfma<<<512, 512, 0, stream>>>(lat, emb, out, wsf);
  vq_finish<<<1, 1, 0, stream>>>(wsf, out, out_size);
}